// Round 1
// baseline (262.077 us; speedup 1.0000x reference)
//
#include <hip/hip_runtime.h>
#include <hip/hip_fp16.h>
#include <hip/hip_cooperative_groups.h>

namespace cg = cooperative_groups;

static constexpr int N  = 100000;
static constexpr int E  = 1600000;

static constexpr int BC     = 1024;                     // block size (16 waves)
static constexpr int NBLK   = 256;                      // grid: 1 block/CU
static constexpr int CHUNKC = E / NBLK;                 // 6250 edges per block
static constexpr int PERC   = (CHUNKC + BC - 1) / BC;   // 7
static constexpr int NBUCK  = (N + 127) / 128;          // 782 buckets of 128 nodes
static constexpr int SLAB   = 3072;                     // slab cap (mean 2048)
static constexpr int GCS    = 16;                       // gcur stride (64 B)
static constexpr int ROUNDS = (NBUCK + NBLK - 1) / NBLK; // 4 bucket rounds

// ---- LDS overlay ------------------------------------------------------------
struct PhC {
    int lhist[NBUCK];
    int lbase[NBUCK];
    int gb[NBUCK];
    int wsum[16];
    int stage[CHUNKC];
};                                   // ~34.4 KB
struct PhD1 {
    int c[128];
    int wq[2];
};
struct PhD2 {
    int   st1[SLAB];
    int   cur[128];
    float acc[128 * 17];
    float sW1[512];
    float sb1[32];
    float sW2[64];
};                                   // ~23.9 KB
struct PhF {
    int st1[SLAB];
};
union Smem {
    PhC  c;
    PhD1 d1;
    PhD2 d2;
    PhF  f;
};

__global__ __launch_bounds__(BC, 1) void kFused(
        const int* __restrict__ src, const int* __restrict__ dst,
        const float4* __restrict__ x4,
        const float* __restrict__ W1, const float* __restrict__ b1,
        const float* __restrict__ W2, const float* __restrict__ b2,
        int* __restrict__ gslab, int* __restrict__ gcur,
        float2* __restrict__ hpre, __half* __restrict__ xpre,
        float2* __restrict__ out) {
    __shared__ Smem sm;
    __shared__ int lofs[ROUNDS][129];   // per-round CSR offsets, persist C->F
    cg::grid_group grid = cg::this_grid();
    int t = threadIdx.x, blk = blockIdx.x;

    // ---- P0: zero slab cursors ---------------------------------------------
    {
        int i = blk * BC + t;
        if (i < NBUCK * GCS) gcur[i] = 0;
    }
    grid.sync();

    // ---- P1: hist + scan + slab reservation + run-copy scatter (old kC) ----
    {
        for (int i = t; i < NBUCK; i += BC) sm.c.lhist[i] = 0;
        __syncthreads();

        int eb = blk * CHUNKC;
        int ds[PERC], ss[PERC];
#pragma unroll
        for (int k = 0; k < PERC; ++k) {
            int idx = k * BC + t;
            if (idx < CHUNKC) {
                ds[k] = dst[eb + idx];
                ss[k] = src[eb + idx];
                atomicAdd(&sm.c.lhist[ds[k] >> 7], 1);
            }
        }
        __syncthreads();

        int lane = t & 63, wv = t >> 6;
        int val = (t < NBUCK) ? sm.c.lhist[t] : 0;
        int inc = val;
#pragma unroll
        for (int off = 1; off < 64; off <<= 1) {
            int u = __shfl_up(inc, off, 64);
            if (lane >= off) inc += u;
        }
        if (lane == 63) sm.c.wsum[wv] = inc;
        __syncthreads();
        if (wv == 0) {
            int wval = (lane < 16) ? sm.c.wsum[lane] : 0;
            int winc = wval;
#pragma unroll
            for (int off = 1; off < 16; off <<= 1) {
                int u = __shfl_up(winc, off, 64);
                if (lane >= off) winc += u;
            }
            if (lane < 16) sm.c.wsum[lane] = winc - wval;
        }
        __syncthreads();
        if (t < NBUCK) sm.c.lbase[t] = sm.c.wsum[wv] + inc - val;
        __syncthreads();

        if (t < NBUCK) {
            int h = sm.c.lhist[t];
            if (h > 0) sm.c.gb[t] = t * SLAB + atomicAdd(&gcur[t * GCS], h);
            sm.c.lhist[t] = 0;
        }
        __syncthreads();

#pragma unroll
        for (int k = 0; k < PERC; ++k) {
            int idx = k * BC + t;
            if (idx < CHUNKC) {
                int d = ds[k], bk = d >> 7;
                int r = atomicAdd(&sm.c.lhist[bk], 1);
                sm.c.stage[sm.c.lbase[bk] + r] = ss[k] | ((d & 127) << 17);
            }
        }
        __syncthreads();

        if (t < NBUCK) {
            int len = sm.c.lhist[t];
            if (len > 0) {
                int s0 = sm.c.lbase[t];
                int g  = sm.c.gb[t];
                int cap = (t + 1) * SLAB - g;      // slab overflow guard
                if (cap < 0) cap = 0;
                if (len > cap) len = cap;
                for (int i = 0; i < len; ++i) gslab[g + i] = sm.c.stage[s0 + i];
            }
        }
    }
    grid.sync();

    // ---- P2: per-bucket degree hist -> lofs (LDS) + fp16 xpre (old kD1) ----
    for (int rd = 0; rd < ROUNDS; ++rd) {
        int b = rd * NBLK + blk;
        bool ok = b < NBUCK;
        if (t < 128) sm.d1.c[t] = 0;
        __syncthreads();

        int ne = 0, base = 0;
        if (ok) {
            ne = min(gcur[b * GCS], SLAB);
            base = b * SLAB;
            int ne4 = ne & ~3;
            for (int k = 4 * t; k < ne4; k += 4 * BC) {
                int4 p4 = *(const int4*)(gslab + base + k);
                atomicAdd(&sm.d1.c[p4.x >> 17], 1);
                atomicAdd(&sm.d1.c[p4.y >> 17], 1);
                atomicAdd(&sm.d1.c[p4.z >> 17], 1);
                atomicAdd(&sm.d1.c[p4.w >> 17], 1);
            }
            if (t < ne - ne4) atomicAdd(&sm.d1.c[gslab[base + ne4 + t] >> 17], 1);
        }
        __syncthreads();

        // exclusive scan of 128 degree counts (2 waves)
        int lane = t & 63, wv = t >> 6;
        int val = (t < 128) ? sm.d1.c[t] : 0;
        int inc = val;
#pragma unroll
        for (int off = 1; off < 64; off <<= 1) {
            int u = __shfl_up(inc, off, 64);
            if (lane >= off) inc += u;
        }
        if (t == 63) sm.d1.wq[0] = inc;
        __syncthreads();
        if (t < 128) lofs[rd][t] = inc - val + ((wv == 1) ? sm.d1.wq[0] : 0);
        if (t == 128) lofs[rd][128] = ne;

        // xpre = fp16(dis * x): 2 lanes/node
        int n = b * 128 + (t >> 1), h = t & 1;
        if (ok && t < 256 && n < N) {
            float dd = rsqrtf((float)(sm.d1.c[t >> 1] + 1));
            float4 u0 = x4[(size_t)n * 4 + h * 2];
            float4 u1 = x4[(size_t)n * 4 + h * 2 + 1];
            ushort4 p0, p1;
            p0.x = __half_as_ushort(__float2half(u0.x * dd));
            p0.y = __half_as_ushort(__float2half(u0.y * dd));
            p0.z = __half_as_ushort(__float2half(u0.z * dd));
            p0.w = __half_as_ushort(__float2half(u0.w * dd));
            p1.x = __half_as_ushort(__float2half(u1.x * dd));
            p1.y = __half_as_ushort(__float2half(u1.y * dd));
            p1.z = __half_as_ushort(__float2half(u1.z * dd));
            p1.w = __half_as_ushort(__float2half(u1.w * dd));
            *(ushort4*)(xpre + (size_t)n * 16 + h * 8)     = p0;
            *(ushort4*)(xpre + (size_t)n * 16 + h * 8 + 4) = p1;
        }
        __syncthreads();   // protect c[] reuse next round
    }
    grid.sync();

    // ---- P3: node-sort + sorted write-back + 8-lane gather + fused dense ---
    for (int i = t; i < 512; i += BC) sm.d2.sW1[i] = W1[i];
    if (t < 32) sm.d2.sb1[t] = b1[t];
    if (t < 64) sm.d2.sW2[t] = W2[t];

    for (int rd = 0; rd < ROUNDS; ++rd) {
        int b = rd * NBLK + blk;
        bool ok = b < NBUCK;
        int base = b * SLAB;
        int ne = lofs[rd][128];
        if (t < 128) sm.d2.cur[t] = 0;
        __syncthreads();

        if (ok) {
            for (int k = t; k < ne; k += BC) {
                int p = gslab[base + k];
                int lo = p >> 17;
                int r = atomicAdd(&sm.d2.cur[lo], 1);
                sm.d2.st1[lofs[rd][lo] + r] = p & 0x1FFFF;
            }
        }
        __syncthreads();

        // persist sorted src list (in-place) so P4 needs no re-sort
        if (ok) for (int k = t; k < ne; k += BC) gslab[base + k] = sm.d2.st1[k];

        // gather: 8 lanes/node = 4-way edge split x 2 feature halves
        int h  = t & 1;
        int e  = (t >> 1) & 3;
        int nl = t >> 3;
        int n  = b * 128 + nl;
        float a0 = 0.f, a1 = 0.f, a2 = 0.f, a3 = 0.f,
              a4 = 0.f, a5 = 0.f, a6 = 0.f, a7 = 0.f;
        if (ok && n < N) {
            int rs = lofs[rd][nl], re = lofs[rd][nl + 1];
            auto add8 = [&](int4 w) {
                float2 q0 = __half22float2(*(__half2*)&w.x);
                float2 q1 = __half22float2(*(__half2*)&w.y);
                float2 q2 = __half22float2(*(__half2*)&w.z);
                float2 q3 = __half22float2(*(__half2*)&w.w);
                a0 += q0.x; a1 += q0.y; a2 += q1.x; a3 += q1.y;
                a4 += q2.x; a5 += q2.y; a6 += q3.x; a7 += q3.y;
            };
            if (e == 0)      // self-loop term, counted once
                add8(*(const int4*)(xpre + (size_t)n * 16 + h * 8));
            int k = rs + e;
            for (; k + 4 < re; k += 8) {
                int s0 = sm.d2.st1[k], s1 = sm.d2.st1[k + 4];
                int4 v0 = *(const int4*)(xpre + (size_t)s0 * 16 + h * 8);
                int4 v1 = *(const int4*)(xpre + (size_t)s1 * 16 + h * 8);
                add8(v0); add8(v1);
            }
            if (k < re)
                add8(*(const int4*)(xpre + (size_t)sm.d2.st1[k] * 16 + h * 8));
        }
        // butterfly over the 4 edge slices (lane bits 1..2)
        a0 += __shfl_xor(a0, 2, 64); a1 += __shfl_xor(a1, 2, 64);
        a2 += __shfl_xor(a2, 2, 64); a3 += __shfl_xor(a3, 2, 64);
        a4 += __shfl_xor(a4, 2, 64); a5 += __shfl_xor(a5, 2, 64);
        a6 += __shfl_xor(a6, 2, 64); a7 += __shfl_xor(a7, 2, 64);
        a0 += __shfl_xor(a0, 4, 64); a1 += __shfl_xor(a1, 4, 64);
        a2 += __shfl_xor(a2, 4, 64); a3 += __shfl_xor(a3, 4, 64);
        a4 += __shfl_xor(a4, 4, 64); a5 += __shfl_xor(a5, 4, 64);
        a6 += __shfl_xor(a6, 4, 64); a7 += __shfl_xor(a7, 4, 64);
        if (ok && n < N && e == 0) {
            float* row = sm.d2.acc + nl * 17 + h * 8;
            row[0] = a0; row[1] = a1; row[2] = a2; row[3] = a3;
            row[4] = a4; row[5] = a5; row[6] = a6; row[7] = a7;
        }
        __syncthreads();

        // fused dense: 16->32 (ReLU) ->2, pre-scaled by dis[n]
        if (ok && t < 128) {
            int n2 = b * 128 + t;
            if (n2 < N) {
                int deg = lofs[rd][t + 1] - lofs[rd][t];
                float dd = rsqrtf((float)(deg + 1));
                const float* row = sm.d2.acc + t * 17;
                float xi[16];
#pragma unroll
                for (int k = 0; k < 16; ++k) xi[k] = row[k] * dd;
                float o0 = 0.f, o1 = 0.f;
#pragma unroll
                for (int c = 0; c < 32; ++c) {
                    float hh = sm.d2.sb1[c];
#pragma unroll
                    for (int k = 0; k < 16; ++k)
                        hh = fmaf(xi[k], sm.d2.sW1[k * 32 + c], hh);
                    hh = fmaxf(hh, 0.f);
                    o0 = fmaf(hh, sm.d2.sW2[c * 2 + 0], o0);
                    o1 = fmaf(hh, sm.d2.sW2[c * 2 + 1], o1);
                }
                hpre[n2] = make_float2(dd * o0, dd * o1);
            }
        }
        __syncthreads();   // protect st1/cur/acc reuse next round
    }
    grid.sync();

    // ---- P4: layer-2 gather over pre-sorted list (no re-sort) --------------
    float b20 = b2[0], b21 = b2[1];
    for (int rd = 0; rd < ROUNDS; ++rd) {
        int b = rd * NBLK + blk;
        bool ok = b < NBUCK;
        int base = b * SLAB;
        int ne = lofs[rd][128];
        if (ok) for (int k = t; k < ne; k += BC) sm.f.st1[k] = gslab[base + k];
        __syncthreads();

        int e8 = t & 7, nl = t >> 3;
        int n = b * 128 + nl;
        float o0 = 0.f, o1 = 0.f;
        int deg = 0;
        if (ok && n < N) {
            int rs = lofs[rd][nl], re = lofs[rd][nl + 1];
            deg = re - rs;
            if (e8 == 0) {
                float2 s = hpre[n];
                o0 = s.x; o1 = s.y;
            }
            int k = rs + e8;
            for (; k + 8 < re; k += 16) {
                float2 v0 = hpre[sm.f.st1[k]];
                float2 v1 = hpre[sm.f.st1[k + 8]];
                o0 += v0.x + v1.x;
                o1 += v0.y + v1.y;
            }
            if (k < re) {
                float2 v = hpre[sm.f.st1[k]];
                o0 += v.x; o1 += v.y;
            }
        }
        o0 += __shfl_xor(o0, 1, 64); o1 += __shfl_xor(o1, 1, 64);
        o0 += __shfl_xor(o0, 2, 64); o1 += __shfl_xor(o1, 2, 64);
        o0 += __shfl_xor(o0, 4, 64); o1 += __shfl_xor(o1, 4, 64);
        if (ok && n < N && e8 == 0) {
            float dd = rsqrtf((float)(deg + 1));
            out[n] = make_float2(fmaf(dd, o0, b20), fmaf(dd, o1, b21));
        }
        __syncthreads();   // protect st1 reuse next round
    }
}

// ---- launcher ---------------------------------------------------------------

extern "C" void kernel_launch(void* const* d_in, const int* in_sizes, int n_in,
                              void* d_out, int out_size, void* d_ws, size_t ws_size,
                              hipStream_t stream) {
    const float* x  = (const float*)d_in[0];
    const int*   ei = (const int*)d_in[1];
    const float* W1 = (const float*)d_in[2];
    const float* b1 = (const float*)d_in[3];
    const float* W2 = (const float*)d_in[4];
    const float* b2 = (const float*)d_in[5];

    const int* srcp = ei;
    const int* dstp = ei + E;
    const float4* x4p = (const float4*)x;

    // workspace layout (4-byte words; xpre offset stays 16 B aligned)
    int*    gslab = (int*)d_ws;                        // NBUCK*SLAB = 2,402,304
    int*    gcur  = gslab + (size_t)NBUCK * SLAB;      // 782*16 = 12,512
    float2* hprep = (float2*)(gcur + NBUCK * GCS);     // 2N floats (byte ofs 9,659,264)
    __half* xprep = (__half*)((float*)hprep + 2 * (size_t)N);  // 16N halfs, 16B-aligned
    float2* outp  = (float2*)d_out;

    void* args[] = {
        (void*)&srcp, (void*)&dstp, (void*)&x4p,
        (void*)&W1, (void*)&b1, (void*)&W2, (void*)&b2,
        (void*)&gslab, (void*)&gcur, (void*)&hprep, (void*)&xprep, (void*)&outp
    };
    hipLaunchCooperativeKernel(kFused, dim3(NBLK), dim3(BC), args, 0, stream);
}

// Round 2
// 128.936 us; speedup vs baseline: 2.0326x; 2.0326x over previous
//
#include <hip/hip_runtime.h>
#include <hip/hip_fp16.h>

static constexpr int N  = 100000;
static constexpr int E  = 1600000;
static constexpr int B  = 256;                     // kD1 block size
static constexpr int BG = 512;                     // kD2/kF block size (4 lanes/node)

static constexpr int BC     = 1024;                // kC block size
static constexpr int NBLKC  = 256;                 // kC grid (uniform, 1 block/CU)
static constexpr int CHUNKC = E / NBLKC;           // 6250 edges per kC block (exact)
static constexpr int PERC   = (CHUNKC + BC - 1) / BC;  // 7
static constexpr int NBUCK  = (N + 127) / 128;     // 782 buckets of 128 nodes
static constexpr int SLAB   = 3072;                // slab cap (mean 2048, +22 sigma)
static constexpr int GCS    = 16;                  // gcur stride (64 B anti-conflict)

// ---- phase C: hist + wave-scan + slab reservation + run-copy write-out ------

__global__ __launch_bounds__(BC) void kC_scatter(
        const int* __restrict__ src, const int* __restrict__ dst,
        int* __restrict__ gcur, int* __restrict__ gslab) {
    __shared__ int lhist[NBUCK];
    __shared__ int lbase[NBUCK];
    __shared__ int gb[NBUCK];
    __shared__ int wsum[16];
    __shared__ int stage[CHUNKC];

    int t = threadIdx.x, blk = blockIdx.x;
    for (int i = t; i < NBUCK; i += BC) lhist[i] = 0;
    __syncthreads();

    int eb = blk * CHUNKC;
    int ds[PERC], ss[PERC];
#pragma unroll
    for (int k = 0; k < PERC; ++k) {
        int idx = k * BC + t;
        if (idx < CHUNKC) {
            ds[k] = dst[eb + idx];
            ss[k] = src[eb + idx];
            atomicAdd(&lhist[ds[k] >> 7], 1);
        }
    }
    __syncthreads();

    // wave-shuffle exclusive scan of lhist[0..NBUCK) (one element per thread)
    int lane = t & 63, wv = t >> 6;
    int val = (t < NBUCK) ? lhist[t] : 0;
    int inc = val;
#pragma unroll
    for (int off = 1; off < 64; off <<= 1) {
        int u = __shfl_up(inc, off, 64);
        if (lane >= off) inc += u;
    }
    if (lane == 63) wsum[wv] = inc;
    __syncthreads();
    if (wv == 0) {
        int wval = (lane < 16) ? wsum[lane] : 0;
        int winc = wval;
#pragma unroll
        for (int off = 1; off < 16; off <<= 1) {
            int u = __shfl_up(winc, off, 64);
            if (lane >= off) winc += u;
        }
        if (lane < 16) wsum[lane] = winc - wval;   // exclusive wave base
    }
    __syncthreads();
    if (t < NBUCK) lbase[t] = wsum[wv] + inc - val;
    __syncthreads();

    // reserve slab ranges; reset lhist as scatter cursor
    if (t < NBUCK) {
        int h = lhist[t];
        if (h > 0) gb[t] = t * SLAB + atomicAdd(&gcur[t * GCS], h);
        lhist[t] = 0;
    }
    __syncthreads();

    // scatter into LDS stage, bucket-major; packed = (dst&127)<<17 | src
#pragma unroll
    for (int k = 0; k < PERC; ++k) {
        int idx = k * BC + t;
        if (idx < CHUNKC) {
            int d = ds[k], b = d >> 7;
            int r = atomicAdd(&lhist[b], 1);
            stage[lbase[b] + r] = ss[k] | ((d & 127) << 17);
        }
    }
    __syncthreads();

    // run-copy write-out: thread t owns bucket t's contiguous run (no search)
    if (t < NBUCK) {
        int len = lhist[t];
        if (len > 0) {
            int s0 = lbase[t];
            int g  = gb[t];
            int cap = (t + 1) * SLAB - g;  // slab overflow guard
            if (cap < 0) cap = 0;
            if (len > cap) len = cap;
            for (int i = 0; i < len; ++i) gslab[g + i] = stage[s0 + i];
        }
    }
}

// ---- phase D1: per-bucket degree hist -> rofs + fp16 xpre -------------------

__global__ void kD1_deg(const int* __restrict__ gcur, const int* __restrict__ gslab,
                        int* __restrict__ rofs, const float4* __restrict__ x4,
                        __half* __restrict__ xpre) {
    __shared__ int c[128];
    __shared__ int wq[2];
    int t = threadIdx.x, b = blockIdx.x;
    if (t < 128) c[t] = 0;
    __syncthreads();

    int ne = min(gcur[b * GCS], SLAB);
    int base = b * SLAB;                       // multiple of 4 -> int4 aligned
    int ne4 = ne & ~3;
    for (int k = 4 * t; k < ne4; k += 4 * B) {
        int4 p4 = *(const int4*)(gslab + base + k);
        atomicAdd(&c[p4.x >> 17], 1);
        atomicAdd(&c[p4.y >> 17], 1);
        atomicAdd(&c[p4.z >> 17], 1);
        atomicAdd(&c[p4.w >> 17], 1);
    }
    if (t < ne - ne4) atomicAdd(&c[gslab[base + ne4 + t] >> 17], 1);
    __syncthreads();

    // exclusive scan of c[0..128) via 2 wave scans
    int lane = t & 63, wv = t >> 6;
    int val = (t < 128) ? c[t] : 0;
    int inc = val;
#pragma unroll
    for (int off = 1; off < 64; off <<= 1) {
        int u = __shfl_up(inc, off, 64);
        if (lane >= off) inc += u;
    }
    if (t == 63) wq[0] = inc;
    __syncthreads();
    if (t < 128) rofs[b * 129 + t] = base + inc - val + ((wv == 1) ? wq[0] : 0);
    if (t == 128) rofs[b * 129 + 128] = base + ne;

    // xpre = fp16(dis * x): 2 lanes/node, 8 halfs each
    int n = b * 128 + (t >> 1), h = t & 1;
    if (n < N) {
        float d = rsqrtf((float)(c[t >> 1] + 1));
        float4 u0 = x4[(size_t)n * 4 + h * 2];
        float4 u1 = x4[(size_t)n * 4 + h * 2 + 1];
        ushort4 p0, p1;
        p0.x = __half_as_ushort(__float2half(u0.x * d));
        p0.y = __half_as_ushort(__float2half(u0.y * d));
        p0.z = __half_as_ushort(__float2half(u0.z * d));
        p0.w = __half_as_ushort(__float2half(u0.w * d));
        p1.x = __half_as_ushort(__float2half(u1.x * d));
        p1.y = __half_as_ushort(__float2half(u1.y * d));
        p1.z = __half_as_ushort(__float2half(u1.z * d));
        p1.w = __half_as_ushort(__float2half(u1.w * d));
        *(ushort4*)(xpre + (size_t)n * 16 + h * 8)     = p0;
        *(ushort4*)(xpre + (size_t)n * 16 + h * 8 + 4) = p1;
    }
}

// ---- phase D2: LDS node-sort (persisted) + 4-lane gather + fused dense ------

__global__ __launch_bounds__(BG) void kD2_agg(
        const __half* __restrict__ xpre, int* __restrict__ gslab,
        const int* __restrict__ rofs, const float* __restrict__ W1,
        const float* __restrict__ b1, const float* __restrict__ W2,
        float2* __restrict__ hpre) {
    __shared__ int st1[SLAB];
    __shared__ int cur[128];
    __shared__ int lofs[129];
    __shared__ float acc[128 * 17];
    __shared__ float sW1[512], sb1[32], sW2[64];
    int t = threadIdx.x, b = blockIdx.x;
    sW1[t] = W1[t];                 // BG == 512 threads, 512 weights
    if (t < 32) sb1[t] = b1[t];
    if (t < 64) sW2[t] = W2[t];
    if (t < 128) cur[t] = 0;
    int base = b * SLAB;
    if (t < 129) lofs[t] = rofs[b * 129 + t] - base;
    __syncthreads();

    int ne = lofs[128];
    // scatter into node-major LDS order (src-only payload)
    for (int k = t; k < ne; k += BG) {
        int p = gslab[base + k];
        int lo = p >> 17;
        int r = atomicAdd(&cur[lo], 1);
        st1[lofs[lo] + r] = p & 0x1FFFF;
    }
    __syncthreads();

    // persist sorted src list (own slab, coalesced) so kF needs no re-sort
    int ne4 = ne & ~3;
    for (int k = 4 * t; k < ne4; k += 4 * BG)
        *(int4*)(gslab + base + k) = *(const int4*)(st1 + k);
    for (int k = ne4 + t; k < ne; k += BG)
        gslab[base + k] = st1[k];

    // register gather: 4 lanes/node = 2 feature halves x 2 edge slices
    int h = t & 1, e = (t >> 1) & 1, nl = t >> 2;
    int n = b * 128 + nl;
    float a0 = 0.f, a1 = 0.f, a2 = 0.f, a3 = 0.f,
          a4 = 0.f, a5 = 0.f, a6 = 0.f, a7 = 0.f;
    if (n < N) {
        auto add8 = [&](int4 w) {
            float2 q0 = __half22float2(*(__half2*)&w.x);
            float2 q1 = __half22float2(*(__half2*)&w.y);
            float2 q2 = __half22float2(*(__half2*)&w.z);
            float2 q3 = __half22float2(*(__half2*)&w.w);
            a0 += q0.x; a1 += q0.y; a2 += q1.x; a3 += q1.y;
            a4 += q2.x; a5 += q2.y; a6 += q3.x; a7 += q3.y;
        };
        int rs = lofs[nl], re = lofs[nl + 1];
        if (e == 0)   // self-loop, counted once per feature half
            add8(*(const int4*)(xpre + (size_t)n * 16 + h * 8));
        int k = rs + e;
        for (; k + 2 < re; k += 4) {
            int s0 = st1[k], s1 = st1[k + 2];
            int4 v0 = *(const int4*)(xpre + (size_t)s0 * 16 + h * 8);
            int4 v1 = *(const int4*)(xpre + (size_t)s1 * 16 + h * 8);
            add8(v0); add8(v1);
        }
        if (k < re)
            add8(*(const int4*)(xpre + (size_t)st1[k] * 16 + h * 8));
    }
    // combine the 2 edge slices (lane bit 1)
    a0 += __shfl_xor(a0, 2, 64); a1 += __shfl_xor(a1, 2, 64);
    a2 += __shfl_xor(a2, 2, 64); a3 += __shfl_xor(a3, 2, 64);
    a4 += __shfl_xor(a4, 2, 64); a5 += __shfl_xor(a5, 2, 64);
    a6 += __shfl_xor(a6, 2, 64); a7 += __shfl_xor(a7, 2, 64);
    if (n < N && e == 0) {
        float* row = acc + nl * 17 + h * 8;
        row[0] = a0; row[1] = a1; row[2] = a2; row[3] = a3;
        row[4] = a4; row[5] = a5; row[6] = a6; row[7] = a7;
    }
    __syncthreads();

    // fused dense: 16->32 (ReLU) ->2, pre-scaled by dis[n]
    if (t < 128) {
        int n2 = b * 128 + t;
        if (n2 < N) {
            int deg = lofs[t + 1] - lofs[t];
            float d = rsqrtf((float)(deg + 1));
            const float* row = acc + t * 17;
            float xi[16];
#pragma unroll
            for (int k = 0; k < 16; ++k) xi[k] = row[k] * d;
            float o0 = 0.f, o1 = 0.f;
#pragma unroll
            for (int c = 0; c < 32; ++c) {
                float hh = sb1[c];
#pragma unroll
                for (int k = 0; k < 16; ++k) hh = fmaf(xi[k], sW1[k * 32 + c], hh);
                hh = fmaxf(hh, 0.f);
                o0 = fmaf(hh, sW2[c * 2 + 0], o0);
                o1 = fmaf(hh, sW2[c * 2 + 1], o1);
            }
            hpre[n2] = make_float2(d * o0, d * o1);
        }
    }
}

// ---- phase F: layer-2 gather over pre-sorted list (no re-sort) --------------

__global__ __launch_bounds__(BG) void kF_l2(
        const float2* __restrict__ hpre, const int* __restrict__ gslab,
        const int* __restrict__ rofs, const float* __restrict__ b2,
        float2* __restrict__ out) {
    __shared__ int st1[SLAB];
    __shared__ int lofs[129];
    int t = threadIdx.x, b = blockIdx.x;
    int base = b * SLAB;
    if (t < 129) lofs[t] = rofs[b * 129 + t] - base;
    __syncthreads();

    int ne = lofs[128];
    // bulk copy of pre-sorted src list (vectorized, coalesced)
    int ne4 = ne & ~3;
    for (int k = 4 * t; k < ne4; k += 4 * BG)
        *(int4*)(st1 + k) = *(const int4*)(gslab + base + k);
    for (int k = ne4 + t; k < ne; k += BG)
        st1[k] = gslab[base + k];
    __syncthreads();

    // 4 edge slices per node
    int e = t & 3, nl = t >> 2;
    int n = b * 128 + nl;
    float o0 = 0.f, o1 = 0.f;
    int deg = 0;
    if (n < N) {
        int rs = lofs[nl], re = lofs[nl + 1];
        deg = re - rs;
        if (e == 0) {
            float2 self = hpre[n];
            o0 = self.x; o1 = self.y;
        }
        int k = rs + e;
        for (; k + 4 < re; k += 8) {
            float2 v0 = hpre[st1[k]];
            float2 v1 = hpre[st1[k + 4]];
            o0 += v0.x + v1.x;
            o1 += v0.y + v1.y;
        }
        if (k < re) {
            float2 v = hpre[st1[k]];
            o0 += v.x; o1 += v.y;
        }
    }
    o0 += __shfl_xor(o0, 1, 64); o1 += __shfl_xor(o1, 1, 64);
    o0 += __shfl_xor(o0, 2, 64); o1 += __shfl_xor(o1, 2, 64);
    if (n < N && e == 0) {
        float d = rsqrtf((float)(deg + 1));
        out[n] = make_float2(fmaf(d, o0, b2[0]), fmaf(d, o1, b2[1]));
    }
}

// ---- launcher ---------------------------------------------------------------

extern "C" void kernel_launch(void* const* d_in, const int* in_sizes, int n_in,
                              void* d_out, int out_size, void* d_ws, size_t ws_size,
                              hipStream_t stream) {
    const float* x  = (const float*)d_in[0];
    const int*   ei = (const int*)d_in[1];
    const float* W1 = (const float*)d_in[2];
    const float* b1 = (const float*)d_in[3];
    const float* W2 = (const float*)d_in[4];
    const float* b2 = (const float*)d_in[5];

    const int* src = ei;
    const int* dst = ei + E;

    // workspace layout (4-byte words; xpre offset stays 16 B aligned)
    int*    gslab = (int*)d_ws;                        // NBUCK*SLAB = 2,402,304
    int*    rofs  = gslab + (size_t)NBUCK * SLAB;      // 782*129 -> pad 100,880
    int*    gcur  = rofs + 100880;                     // 782*16 = 12,512
    float*  hpre  = (float*)(gcur + 12512);            // 2N
    __half* xpre  = (__half*)(hpre + 2 * (size_t)N);   // 16N halfs (3.2 MB)

    hipMemsetAsync(gcur, 0, NBUCK * GCS * sizeof(int), stream);
    kC_scatter<<<NBLKC, BC, 0, stream>>>(src, dst, gcur, gslab);
    kD1_deg<<<NBUCK, B, 0, stream>>>(gcur, gslab, rofs, (const float4*)x, xpre);
    kD2_agg<<<NBUCK, BG, 0, stream>>>(xpre, gslab, rofs, W1, b1, W2, (float2*)hpre);
    kF_l2<<<NBUCK, BG, 0, stream>>>((const float2*)hpre, gslab, rofs, b2,
                                    (float2*)d_out);
}